// Round 1
// baseline (230.461 us; speedup 1.0000x reference)
//
#include <hip/hip_runtime.h>
#include <hip/hip_bf16.h>
#include <math.h>

#define SEQ 2048
#define NH  16
#define HD  64

typedef __attribute__((ext_vector_type(8))) short bf16x8;
typedef __attribute__((ext_vector_type(4))) float f32x4;

static __device__ inline short f2bf(float f) {
  union { float f; unsigned u; } x; x.f = f;
  unsigned u = x.u;
  unsigned r = (u + 0x7fffu + ((u >> 16) & 1u)) >> 16;  // RNE
  return (short)r;
}

// One wave (64 threads) handles 16 query rows of one head.
// QK^T and PV via v_mfma_f32_16x16x32_bf16.
// A-frag: row = lane&15, k = (lane>>4)*8 + i
// B-frag: col = lane&15, k = (lane>>4)*8 + i
// C/D:    col = lane&15, row = (lane>>4)*4 + reg
__global__ __launch_bounds__(64) void attn_fwd_kernel(
    const float* __restrict__ Q, const float* __restrict__ K,
    const float* __restrict__ V, float* __restrict__ Out) {
  const int lane = threadIdx.x & 63;
  const int lr = lane & 15;   // row (A) / col (B, C)
  const int lg = lane >> 4;   // group 0..3
  const int q0 = blockIdx.x * 16;
  const size_t hb = (size_t)blockIdx.y * SEQ * HD;

  const float LOG2E = 1.4426950408889634f;

  // ---- Q fragments (pre-scaled by 1/sqrt(D) = 0.125, exact in bf16) ----
  bf16x8 qa[2];
  {
    const float* qrow = Q + hb + (size_t)(q0 + lr) * HD;
#pragma unroll
    for (int dh = 0; dh < 2; ++dh) {
      const float* p = qrow + dh * 32 + lg * 8;
      bf16x8 t;
#pragma unroll
      for (int i = 0; i < 8; ++i) t[i] = f2bf(p[i] * 0.125f);
      qa[dh] = t;
    }
  }

  f32x4 o[4];
#pragma unroll
  for (int dt = 0; dt < 4; ++dt) o[dt] = (f32x4){0.f, 0.f, 0.f, 0.f};
  float m[4], ll[4];
#pragma unroll
  for (int r = 0; r < 4; ++r) { m[r] = -INFINITY; ll[r] = 0.f; }

  __shared__ float plds[16][33];  // P bounce buffer (C-layout -> A-layout)

  const int nsteps = (q0 + 16 + 31) >> 5;  // causal: cols <= q0+15 needed
  for (int s = 0; s < nsteps; ++s) {
    const int k0 = s * 32;

    // ---- K fragments ----
    bf16x8 kb[2][2];  // [col-tile][d-half]
#pragma unroll
    for (int ct = 0; ct < 2; ++ct) {
      const float* krow = K + hb + (size_t)(k0 + ct * 16 + lr) * HD;
#pragma unroll
      for (int dh = 0; dh < 2; ++dh) {
        const float* p = krow + dh * 32 + lg * 8;
        bf16x8 t;
#pragma unroll
        for (int i = 0; i < 8; ++i) t[i] = f2bf(p[i]);
        kb[ct][dh] = t;
      }
    }

    // ---- S = (Q*scale) @ K^T  (two 16x16 col-tiles, K=64 chained) ----
    f32x4 sc[2];
#pragma unroll
    for (int ct = 0; ct < 2; ++ct) {
      f32x4 z = (f32x4){0.f, 0.f, 0.f, 0.f};
      z = __builtin_amdgcn_mfma_f32_16x16x32_bf16(qa[0], kb[ct][0], z, 0, 0, 0);
      z = __builtin_amdgcn_mfma_f32_16x16x32_bf16(qa[1], kb[ct][1], z, 0, 0, 0);
      sc[ct] = z;
    }

    // ---- causal mask (only the last step can touch the diagonal) ----
    if (s == nsteps - 1) {
#pragma unroll
      for (int ct = 0; ct < 2; ++ct)
#pragma unroll
        for (int r = 0; r < 4; ++r) {
          int col = k0 + ct * 16 + lr;
          int row = q0 + 4 * lg + r;
          if (col > row) sc[ct][r] = -INFINITY;
        }
    }

    // ---- online softmax (rows live in 16-lane groups) ----
    float mx[4];
#pragma unroll
    for (int r = 0; r < 4; ++r) mx[r] = fmaxf(sc[0][r], sc[1][r]);
#pragma unroll
    for (int off = 1; off < 16; off <<= 1)
#pragma unroll
      for (int r = 0; r < 4; ++r) mx[r] = fmaxf(mx[r], __shfl_xor(mx[r], off, 64));

    float fac[4], pr[2][4], rs[4];
#pragma unroll
    for (int r = 0; r < 4; ++r) {
      float mn = fmaxf(m[r], mx[r]);
      fac[r] = exp2f((m[r] - mn) * LOG2E);  // exp(m_old - mn); -inf -> 0
      m[r] = mn;
      float sum = 0.f;
#pragma unroll
      for (int ct = 0; ct < 2; ++ct) {
        float p = exp2f((sc[ct][r] - mn) * LOG2E);
        pr[ct][r] = p;
        sum += p;
      }
      rs[r] = sum;
    }
#pragma unroll
    for (int off = 1; off < 16; off <<= 1)
#pragma unroll
      for (int r = 0; r < 4; ++r) rs[r] += __shfl_xor(rs[r], off, 64);
#pragma unroll
    for (int r = 0; r < 4; ++r) ll[r] = ll[r] * fac[r] + rs[r];
#pragma unroll
    for (int dt = 0; dt < 4; ++dt)
#pragma unroll
      for (int r = 0; r < 4; ++r) o[dt][r] *= fac[r];

    // ---- P: C-layout -> A-layout through LDS ----
    __syncthreads();  // previous iteration's reads done before overwrite
#pragma unroll
    for (int ct = 0; ct < 2; ++ct)
#pragma unroll
      for (int r = 0; r < 4; ++r)
        plds[4 * lg + r][ct * 16 + lr] = pr[ct][r];
    __syncthreads();
    bf16x8 pa;
    {
      const float* p = &plds[lr][lg * 8];
#pragma unroll
      for (int i = 0; i < 8; ++i) pa[i] = f2bf(p[i]);
    }

    // ---- O += P @ V ----
#pragma unroll
    for (int dt = 0; dt < 4; ++dt) {
      const float* vcol = V + hb + (size_t)(k0 + lg * 8) * HD + dt * 16 + lr;
      bf16x8 vb;
#pragma unroll
      for (int i = 0; i < 8; ++i) vb[i] = f2bf(vcol[(size_t)i * HD]);
      o[dt] = __builtin_amdgcn_mfma_f32_16x16x32_bf16(pa, vb, o[dt], 0, 0, 0);
    }
  }

  // ---- epilogue: normalize and store ----
#pragma unroll
  for (int dt = 0; dt < 4; ++dt)
#pragma unroll
    for (int r = 0; r < 4; ++r) {
      int row = q0 + 4 * lg + r;
      Out[hb + (size_t)row * HD + dt * 16 + lr] = o[dt][r] / ll[r];
    }
}

extern "C" void kernel_launch(void* const* d_in, const int* in_sizes, int n_in,
                              void* d_out, int out_size, void* d_ws, size_t ws_size,
                              hipStream_t stream) {
  const float* q = (const float*)d_in[0];
  const float* k = (const float*)d_in[1];
  const float* v = (const float*)d_in[2];
  float* out = (float*)d_out;
  dim3 grid(SEQ / 16, NH);
  attn_fwd_kernel<<<grid, dim3(64), 0, stream>>>(q, k, v, out);
}

// Round 3
// 132.969 us; speedup vs baseline: 1.7332x; 1.7332x over previous
//
#include <hip/hip_runtime.h>
#include <hip/hip_bf16.h>
#include <math.h>

#define SEQ 2048
#define NH  16
#define HD  64

typedef __attribute__((ext_vector_type(8))) short bf16x8;
typedef __attribute__((ext_vector_type(4))) float f32x4;

static __device__ inline short f2bf(float f) {
  union { float f; unsigned u; } x; x.f = f;
  unsigned u = x.u;
  unsigned r = (u + 0x7fffu + ((u >> 16) & 1u)) >> 16;  // RNE
  return (short)r;
}

// ---------------- prepass: K f32 -> bf16, same [H][S][D] layout ----------------
__global__ __launch_bounds__(256) void conv_k_kernel(const float* __restrict__ K,
                                                     short* __restrict__ Kb) {
  const size_t i = ((size_t)blockIdx.x * 256 + threadIdx.x) * 8;
  float4 a = *(const float4*)(K + i);
  float4 b = *(const float4*)(K + i + 4);
  bf16x8 t;
  t[0] = f2bf(a.x); t[1] = f2bf(a.y); t[2] = f2bf(a.z); t[3] = f2bf(a.w);
  t[4] = f2bf(b.x); t[5] = f2bf(b.y); t[6] = f2bf(b.z); t[7] = f2bf(b.w);
  *(bf16x8*)(Kb + i) = t;
}

// ---------------- prepass: V f32 [H][S][D] -> bf16 transposed [H][D][S] --------
__global__ __launch_bounds__(256) void conv_vt_kernel(const float* __restrict__ V,
                                                      short* __restrict__ Vt) {
  __shared__ short tile[64][72];  // 64 s-rows x 64 d, padded
  const int h = blockIdx.y;
  const int s0 = blockIdx.x * 64;
  const int t = threadIdx.x;
  const int r = t >> 2;           // 0..63
  const int c0 = (t & 3) * 16;    // 0,16,32,48

  const float* src = V + ((size_t)h * SEQ + s0 + r) * HD + c0;
#pragma unroll
  for (int j = 0; j < 4; ++j) {
    float4 a = *(const float4*)(src + j * 4);
    tile[r][c0 + j * 4 + 0] = f2bf(a.x);
    tile[r][c0 + j * 4 + 1] = f2bf(a.y);
    tile[r][c0 + j * 4 + 2] = f2bf(a.z);
    tile[r][c0 + j * 4 + 3] = f2bf(a.w);
  }
  __syncthreads();
  // write row d=r, s-cols s0+c0 .. +15
  short* dst = Vt + ((size_t)h * HD + r) * SEQ + s0 + c0;
  bf16x8 o0, o1;
#pragma unroll
  for (int j = 0; j < 8; ++j) o0[j] = tile[c0 + j][r];
#pragma unroll
  for (int j = 0; j < 8; ++j) o1[j] = tile[c0 + 8 + j][r];
  *(bf16x8*)(dst) = o0;
  *(bf16x8*)(dst + 8) = o1;
}

// ---------------- main: 1 wave per 16 q-rows, KVBLK=64 -------------------------
// A-frag: row = lane&15, k = (lane>>4)*8 + i
// B-frag: col = lane&15, k = (lane>>4)*8 + i
// C/D:    col = lane&15, row = (lane>>4)*4 + reg
__global__ __launch_bounds__(64) void attn_fwd_kernel(
    const float* __restrict__ Q, const short* __restrict__ Kb,
    const short* __restrict__ Vt, float* __restrict__ Out) {
  const int lane = threadIdx.x & 63;
  const int lr = lane & 15;
  const int lg = lane >> 4;
  const int qt = gridDim.x - 1 - blockIdx.x;  // heavy tiles dispatched first
  const int q0 = qt * 16;
  const int h = blockIdx.y;
  const size_t hqb = (size_t)h * SEQ * HD;
  const short* Kh = Kb + (size_t)h * SEQ * HD;
  const short* Vh = Vt + (size_t)h * HD * SEQ;

  const float LOG2E = 1.4426950408889634f;

  // Q fragments, pre-scaled by 1/sqrt(64)=0.125 (exact in bf16)
  bf16x8 qa[2];
  {
    const float* qrow = Q + hqb + (size_t)(q0 + lr) * HD;
#pragma unroll
    for (int dh = 0; dh < 2; ++dh) {
      const float* p = qrow + dh * 32 + lg * 8;
      bf16x8 t;
#pragma unroll
      for (int i = 0; i < 8; ++i) t[i] = f2bf(p[i] * 0.125f);
      qa[dh] = t;
    }
  }

  f32x4 o[4];
#pragma unroll
  for (int dt = 0; dt < 4; ++dt) o[dt] = (f32x4){0.f, 0.f, 0.f, 0.f};
  float m[4], ll[4];
#pragma unroll
  for (int r = 0; r < 4; ++r) { m[r] = -INFINITY; ll[r] = 0.f; }

  __shared__ float plds[16][68];  // P bounce (C-layout -> A-layout); 68: b128-aligned rows, ~2-way banks

  const int nsteps = (q0 + 16 + 63) >> 6;  // causal
  for (int s = 0; s < nsteps; ++s) {
    const int k0 = s * 64;

    // K fragments: 4 col-tiles x 2 d-halves, 16B vector loads
    bf16x8 kb[4][2];
#pragma unroll
    for (int ct = 0; ct < 4; ++ct) {
      const short* krow = Kh + (size_t)(k0 + ct * 16 + lr) * HD;
#pragma unroll
      for (int dh = 0; dh < 2; ++dh)
        kb[ct][dh] = *(const bf16x8*)(krow + dh * 32 + lg * 8);
    }

    // S = (Q*scale) @ K^T : 4 16x16 col-tiles, K=64 chained
    f32x4 sc[4];
#pragma unroll
    for (int ct = 0; ct < 4; ++ct) {
      f32x4 z = (f32x4){0.f, 0.f, 0.f, 0.f};
      z = __builtin_amdgcn_mfma_f32_16x16x32_bf16(qa[0], kb[ct][0], z, 0, 0, 0);
      z = __builtin_amdgcn_mfma_f32_16x16x32_bf16(qa[1], kb[ct][1], z, 0, 0, 0);
      sc[ct] = z;
    }

    // causal mask: only last tile can cross the diagonal
    if (s == nsteps - 1) {
#pragma unroll
      for (int ct = 0; ct < 4; ++ct)
#pragma unroll
        for (int r = 0; r < 4; ++r) {
          int col = k0 + ct * 16 + lr;
          int row = q0 + 4 * lg + r;
          if (col > row) sc[ct][r] = -INFINITY;
        }
    }

    // online softmax (row = 4*lg + r lives across the 16 lanes lr)
    float mx[4];
#pragma unroll
    for (int r = 0; r < 4; ++r)
      mx[r] = fmaxf(fmaxf(sc[0][r], sc[1][r]), fmaxf(sc[2][r], sc[3][r]));
#pragma unroll
    for (int off = 1; off < 16; off <<= 1)
#pragma unroll
      for (int r = 0; r < 4; ++r) mx[r] = fmaxf(mx[r], __shfl_xor(mx[r], off, 64));

    float fac[4], rs[4];
    float pr[4][4];
#pragma unroll
    for (int r = 0; r < 4; ++r) {
      float mn = fmaxf(m[r], mx[r]);
      fac[r] = exp2f((m[r] - mn) * LOG2E);
      m[r] = mn;
      float sum = 0.f;
#pragma unroll
      for (int ct = 0; ct < 4; ++ct) {
        float p = exp2f((sc[ct][r] - mn) * LOG2E);
        pr[ct][r] = p;
        sum += p;
      }
      rs[r] = sum;
    }
#pragma unroll
    for (int off = 1; off < 16; off <<= 1)
#pragma unroll
      for (int r = 0; r < 4; ++r) rs[r] += __shfl_xor(rs[r], off, 64);
#pragma unroll
    for (int r = 0; r < 4; ++r) ll[r] = ll[r] * fac[r] + rs[r];
#pragma unroll
    for (int dt = 0; dt < 4; ++dt)
#pragma unroll
      for (int r = 0; r < 4; ++r) o[dt][r] *= fac[r];

    // P bounce: C-layout -> A-layout via LDS
    __syncthreads();
#pragma unroll
    for (int ct = 0; ct < 4; ++ct)
#pragma unroll
      for (int r = 0; r < 4; ++r)
        plds[4 * lg + r][ct * 16 + lr] = pr[ct][r];
    __syncthreads();
    bf16x8 pa[2];
#pragma unroll
    for (int kh = 0; kh < 2; ++kh) {
      const float* p = &plds[lr][kh * 32 + lg * 8];
      f32x4 w0 = *(const f32x4*)(p);
      f32x4 w1 = *(const f32x4*)(p + 4);
      bf16x8 t;
      t[0] = f2bf(w0[0]); t[1] = f2bf(w0[1]); t[2] = f2bf(w0[2]); t[3] = f2bf(w0[3]);
      t[4] = f2bf(w1[0]); t[5] = f2bf(w1[1]); t[6] = f2bf(w1[2]); t[7] = f2bf(w1[3]);
      pa[kh] = t;
    }

    // O += P @ V : V^T loads are contiguous 16B
#pragma unroll
    for (int dt = 0; dt < 4; ++dt) {
      const short* vrow = Vh + (size_t)(dt * 16 + lr) * SEQ + k0 + lg * 8;
      bf16x8 vb0 = *(const bf16x8*)(vrow);
      bf16x8 vb1 = *(const bf16x8*)(vrow + 32);
      o[dt] = __builtin_amdgcn_mfma_f32_16x16x32_bf16(pa[0], vb0, o[dt], 0, 0, 0);
      o[dt] = __builtin_amdgcn_mfma_f32_16x16x32_bf16(pa[1], vb1, o[dt], 0, 0, 0);
    }
  }

  // epilogue
#pragma unroll
  for (int dt = 0; dt < 4; ++dt)
#pragma unroll
    for (int r = 0; r < 4; ++r) {
      int row = q0 + 4 * lg + r;
      Out[hqb + (size_t)row * HD + dt * 16 + lr] = o[dt][r] / ll[r];
    }
}

// ---------------- fallback (round-1 self-contained kernel) ---------------------
__global__ __launch_bounds__(64) void attn_fwd_fallback(
    const float* __restrict__ Q, const float* __restrict__ K,
    const float* __restrict__ V, float* __restrict__ Out) {
  const int lane = threadIdx.x & 63;
  const int lr = lane & 15;
  const int lg = lane >> 4;
  const int q0 = blockIdx.x * 16;
  const size_t hb = (size_t)blockIdx.y * SEQ * HD;
  const float LOG2E = 1.4426950408889634f;

  bf16x8 qa[2];
  {
    const float* qrow = Q + hb + (size_t)(q0 + lr) * HD;
#pragma unroll
    for (int dh = 0; dh < 2; ++dh) {
      const float* p = qrow + dh * 32 + lg * 8;
      bf16x8 t;
#pragma unroll
      for (int i = 0; i < 8; ++i) t[i] = f2bf(p[i] * 0.125f);
      qa[dh] = t;
    }
  }
  f32x4 o[4];
#pragma unroll
  for (int dt = 0; dt < 4; ++dt) o[dt] = (f32x4){0.f, 0.f, 0.f, 0.f};
  float m[4], ll[4];
#pragma unroll
  for (int r = 0; r < 4; ++r) { m[r] = -INFINITY; ll[r] = 0.f; }
  __shared__ float plds[16][33];
  const int nsteps = (q0 + 16 + 31) >> 5;
  for (int s = 0; s < nsteps; ++s) {
    const int k0 = s * 32;
    bf16x8 kb[2][2];
#pragma unroll
    for (int ct = 0; ct < 2; ++ct) {
      const float* krow = K + hb + (size_t)(k0 + ct * 16 + lr) * HD;
#pragma unroll
      for (int dh = 0; dh < 2; ++dh) {
        const float* p = krow + dh * 32 + lg * 8;
        bf16x8 t;
#pragma unroll
        for (int i = 0; i < 8; ++i) t[i] = f2bf(p[i]);
        kb[ct][dh] = t;
      }
    }
    f32x4 sc[2];
#pragma unroll
    for (int ct = 0; ct < 2; ++ct) {
      f32x4 z = (f32x4){0.f, 0.f, 0.f, 0.f};
      z = __builtin_amdgcn_mfma_f32_16x16x32_bf16(qa[0], kb[ct][0], z, 0, 0, 0);
      z = __builtin_amdgcn_mfma_f32_16x16x32_bf16(qa[1], kb[ct][1], z, 0, 0, 0);
      sc[ct] = z;
    }
    if (s == nsteps - 1) {
#pragma unroll
      for (int ct = 0; ct < 2; ++ct)
#pragma unroll
        for (int r = 0; r < 4; ++r) {
          int col = k0 + ct * 16 + lr;
          int row = q0 + 4 * lg + r;
          if (col > row) sc[ct][r] = -INFINITY;
        }
    }
    float mx[4];
#pragma unroll
    for (int r = 0; r < 4; ++r) mx[r] = fmaxf(sc[0][r], sc[1][r]);
#pragma unroll
    for (int off = 1; off < 16; off <<= 1)
#pragma unroll
      for (int r = 0; r < 4; ++r) mx[r] = fmaxf(mx[r], __shfl_xor(mx[r], off, 64));
    float fac[4], pr[2][4], rs[4];
#pragma unroll
    for (int r = 0; r < 4; ++r) {
      float mn = fmaxf(m[r], mx[r]);
      fac[r] = exp2f((m[r] - mn) * LOG2E);
      m[r] = mn;
      float sum = 0.f;
#pragma unroll
      for (int ct = 0; ct < 2; ++ct) {
        float p = exp2f((sc[ct][r] - mn) * LOG2E);
        pr[ct][r] = p;
        sum += p;
      }
      rs[r] = sum;
    }
#pragma unroll
    for (int off = 1; off < 16; off <<= 1)
#pragma unroll
      for (int r = 0; r < 4; ++r) rs[r] += __shfl_xor(rs[r], off, 64);
#pragma unroll
    for (int r = 0; r < 4; ++r) ll[r] = ll[r] * fac[r] + rs[r];
#pragma unroll
    for (int dt = 0; dt < 4; ++dt)
#pragma unroll
      for (int r = 0; r < 4; ++r) o[dt][r] *= fac[r];
    __syncthreads();
#pragma unroll
    for (int ct = 0; ct < 2; ++ct)
#pragma unroll
      for (int r = 0; r < 4; ++r)
        plds[4 * lg + r][ct * 16 + lr] = pr[ct][r];
    __syncthreads();
    bf16x8 pa;
    {
      const float* p = &plds[lr][lg * 8];
#pragma unroll
      for (int i = 0; i < 8; ++i) pa[i] = f2bf(p[i]);
    }
#pragma unroll
    for (int dt = 0; dt < 4; ++dt) {
      const float* vcol = V + hb + (size_t)(k0 + lg * 8) * HD + dt * 16 + lr;
      bf16x8 vb;
#pragma unroll
      for (int i = 0; i < 8; ++i) vb[i] = f2bf(vcol[(size_t)i * HD]);
      o[dt] = __builtin_amdgcn_mfma_f32_16x16x32_bf16(pa, vb, o[dt], 0, 0, 0);
    }
  }
#pragma unroll
  for (int dt = 0; dt < 4; ++dt)
#pragma unroll
    for (int r = 0; r < 4; ++r) {
      int row = q0 + 4 * lg + r;
      Out[hb + (size_t)row * HD + dt * 16 + lr] = o[dt][r] / ll[r];
    }
}

extern "C" void kernel_launch(void* const* d_in, const int* in_sizes, int n_in,
                              void* d_out, int out_size, void* d_ws, size_t ws_size,
                              hipStream_t stream) {
  const float* q = (const float*)d_in[0];
  const float* k = (const float*)d_in[1];
  const float* v = (const float*)d_in[2];
  float* out = (float*)d_out;

  const size_t elems = (size_t)NH * SEQ * HD;      // 2,097,152
  const size_t need = 2 * elems * sizeof(short);   // 8 MB

  if (ws_size >= need) {
    short* Kb = (short*)d_ws;
    short* Vt = Kb + elems;
    conv_k_kernel<<<(int)(elems / (8 * 256)), 256, 0, stream>>>(k, Kb);
    conv_vt_kernel<<<dim3(SEQ / 64, NH), 256, 0, stream>>>(v, Vt);
    attn_fwd_kernel<<<dim3(SEQ / 16, NH), dim3(64), 0, stream>>>(q, Kb, Vt, out);
  } else {
    attn_fwd_fallback<<<dim3(SEQ / 16, NH), dim3(64), 0, stream>>>(q, k, v, out);
  }
}

// Round 4
// 109.619 us; speedup vs baseline: 2.1024x; 1.2130x over previous
//
#include <hip/hip_runtime.h>
#include <hip/hip_bf16.h>
#include <math.h>

#define SEQ 2048
#define NH  16
#define HD  64
#define NW  4   // waves per block (KV split factor)

typedef __attribute__((ext_vector_type(8))) short bf16x8;
typedef __attribute__((ext_vector_type(4))) float f32x4;

static __device__ inline short f2bf(float f) {
  union { float f; unsigned u; } x; x.f = f;
  unsigned u = x.u;
  unsigned r = (u + 0x7fffu + ((u >> 16) & 1u)) >> 16;  // RNE
  return (short)r;
}

// ---- fused prepass: K f32->bf16 (same layout) + V f32->bf16 transposed [H][D][S]
__global__ __launch_bounds__(256) void conv_kv_kernel(
    const float* __restrict__ K, const float* __restrict__ V,
    short* __restrict__ Kb, short* __restrict__ Vt) {
  __shared__ short tile[64][72];
  const int h = blockIdx.y;
  const int s0 = blockIdx.x * 64;
  const int t = threadIdx.x;
  const int r = t >> 2;           // 0..63  (s-row within tile / d-row for output)
  const int c0 = (t & 3) * 16;    // 0,16,32,48

  const size_t rowoff = ((size_t)h * SEQ + s0 + r) * HD + c0;

  // K: straight convert, 16 elems/thread
  {
    const float* ks = K + rowoff;
    bf16x8 k0, k1;
#pragma unroll
    for (int j = 0; j < 2; ++j) {
      float4 a = *(const float4*)(ks + j * 8);
      float4 b = *(const float4*)(ks + j * 8 + 4);
      bf16x8 o;
      o[0] = f2bf(a.x); o[1] = f2bf(a.y); o[2] = f2bf(a.z); o[3] = f2bf(a.w);
      o[4] = f2bf(b.x); o[5] = f2bf(b.y); o[6] = f2bf(b.z); o[7] = f2bf(b.w);
      if (j == 0) k0 = o; else k1 = o;
    }
    short* kd = Kb + rowoff;
    *(bf16x8*)(kd) = k0;
    *(bf16x8*)(kd + 8) = k1;
  }

  // V: convert into LDS tile, then write transposed
  {
    const float* vs = V + rowoff;
#pragma unroll
    for (int j = 0; j < 4; ++j) {
      float4 a = *(const float4*)(vs + j * 4);
      tile[r][c0 + j * 4 + 0] = f2bf(a.x);
      tile[r][c0 + j * 4 + 1] = f2bf(a.y);
      tile[r][c0 + j * 4 + 2] = f2bf(a.z);
      tile[r][c0 + j * 4 + 3] = f2bf(a.w);
    }
    __syncthreads();
    short* dst = Vt + ((size_t)h * HD + r) * SEQ + s0 + c0;
    bf16x8 o0, o1;
#pragma unroll
    for (int j = 0; j < 8; ++j) o0[j] = tile[c0 + j][r];
#pragma unroll
    for (int j = 0; j < 8; ++j) o1[j] = tile[c0 + 8 + j][r];
    *(bf16x8*)(dst) = o0;
    *(bf16x8*)(dst + 8) = o1;
  }
}

// ---- main: 1 block (4 waves) per 16 q-rows; waves split the KV dimension ------
// A-frag: row = lane&15, k = (lane>>4)*8 + i
// B-frag: col = lane&15, k = (lane>>4)*8 + i
// C/D:    col = lane&15, row = (lane>>4)*4 + reg
// Softmax runs in log2 domain (LOG2E folded into Q prescale).
__global__ __launch_bounds__(256, 4) void attn_fwd_kernel(
    const float* __restrict__ Q, const short* __restrict__ Kb,
    const short* __restrict__ Vt, float* __restrict__ Out) {
  const int tid = threadIdx.x;
  const int w = tid >> 6;      // wave id 0..3
  const int lane = tid & 63;
  const int lr = lane & 15;
  const int lg = lane >> 4;
  const int qt = gridDim.x - 1 - blockIdx.x;  // heavy tiles first
  const int q0 = qt * 16;
  const int h = blockIdx.y;
  const size_t hqb = (size_t)h * SEQ * HD;
  const short* Kh = Kb + (size_t)h * SEQ * HD;
  const short* Vh = Vt + (size_t)h * HD * SEQ;

  // smem: [0,16384) o-partials [w][dt][r][lane]; [16384,20480) m; [20480,24576) l
  // in-loop: per-wave P bounce [16][68] f32 at w*4352 (aliases; barrier-separated)
  __shared__ __align__(16) char smem[24576];
  float (*plds)[68] = (float(*)[68])(smem + w * 4352);
  float* obp = (float*)smem;
  float* mbp = (float*)(smem + 16384);
  float* lbp = (float*)(smem + 20480);

  // Q fragments, pre-scaled by 0.125 * log2(e)  (log2-domain softmax)
  const float QSCALE = 0.125f * 1.4426950408889634f;
  bf16x8 qa[2];
  {
    const float* qrow = Q + hqb + (size_t)(q0 + lr) * HD;
#pragma unroll
    for (int dh = 0; dh < 2; ++dh) {
      const float* p = qrow + dh * 32 + lg * 8;
      bf16x8 t;
#pragma unroll
      for (int i = 0; i < 8; ++i) t[i] = f2bf(p[i] * QSCALE);
      qa[dh] = t;
    }
  }

  f32x4 o[4];
#pragma unroll
  for (int dt = 0; dt < 4; ++dt) o[dt] = (f32x4){0.f, 0.f, 0.f, 0.f};
  float m[4], ll[4];
#pragma unroll
  for (int r = 0; r < 4; ++r) { m[r] = -INFINITY; ll[r] = 0.f; }

  const int nsteps = (q0 + 16 + 63) >> 6;  // causal tile count
  for (int s = w; s < nsteps; s += NW) {
    const int k0 = s * 64;

    bf16x8 kb[4][2];
#pragma unroll
    for (int ct = 0; ct < 4; ++ct) {
      const short* krow = Kh + (size_t)(k0 + ct * 16 + lr) * HD;
#pragma unroll
      for (int dh = 0; dh < 2; ++dh)
        kb[ct][dh] = *(const bf16x8*)(krow + dh * 32 + lg * 8);
    }

    f32x4 sc[4];
#pragma unroll
    for (int ct = 0; ct < 4; ++ct) {
      f32x4 z = (f32x4){0.f, 0.f, 0.f, 0.f};
      z = __builtin_amdgcn_mfma_f32_16x16x32_bf16(qa[0], kb[ct][0], z, 0, 0, 0);
      z = __builtin_amdgcn_mfma_f32_16x16x32_bf16(qa[1], kb[ct][1], z, 0, 0, 0);
      sc[ct] = z;
    }

    if (s == nsteps - 1) {  // only the diagonal tile masks
#pragma unroll
      for (int ct = 0; ct < 4; ++ct)
#pragma unroll
        for (int r = 0; r < 4; ++r) {
          int col = k0 + ct * 16 + lr;
          int row = q0 + 4 * lg + r;
          if (col > row) sc[ct][r] = -INFINITY;
        }
    }

    // online softmax in log2 domain; rows live across the 16 lanes lr
    float mx[4];
#pragma unroll
    for (int r = 0; r < 4; ++r)
      mx[r] = fmaxf(fmaxf(sc[0][r], sc[1][r]), fmaxf(sc[2][r], sc[3][r]));
#pragma unroll
    for (int off = 1; off < 16; off <<= 1)
#pragma unroll
      for (int r = 0; r < 4; ++r) mx[r] = fmaxf(mx[r], __shfl_xor(mx[r], off, 64));

    float fac[4], rs[4];
    float pr[4][4];
#pragma unroll
    for (int r = 0; r < 4; ++r) {
      float mn = fmaxf(m[r], mx[r]);
      fac[r] = exp2f(m[r] - mn);
      m[r] = mn;
      float sum = 0.f;
#pragma unroll
      for (int ct = 0; ct < 4; ++ct) {
        float p = exp2f(sc[ct][r] - mn);
        pr[ct][r] = p;
        sum += p;
      }
      rs[r] = sum;
    }
#pragma unroll
    for (int off = 1; off < 16; off <<= 1)
#pragma unroll
      for (int r = 0; r < 4; ++r) rs[r] += __shfl_xor(rs[r], off, 64);
#pragma unroll
    for (int r = 0; r < 4; ++r) ll[r] = ll[r] * fac[r] + rs[r];
#pragma unroll
    for (int dt = 0; dt < 4; ++dt)
#pragma unroll
      for (int r = 0; r < 4; ++r) o[dt][r] *= fac[r];

    // P: C-layout -> A-layout via per-wave LDS (no cross-wave barrier needed)
#pragma unroll
    for (int ct = 0; ct < 4; ++ct)
#pragma unroll
      for (int r = 0; r < 4; ++r)
        plds[4 * lg + r][ct * 16 + lr] = pr[ct][r];
    bf16x8 pa[2];
#pragma unroll
    for (int kh = 0; kh < 2; ++kh) {
      const float* p = &plds[lr][kh * 32 + lg * 8];
      f32x4 w0 = *(const f32x4*)(p);
      f32x4 w1 = *(const f32x4*)(p + 4);
      bf16x8 t;
      t[0] = f2bf(w0[0]); t[1] = f2bf(w0[1]); t[2] = f2bf(w0[2]); t[3] = f2bf(w0[3]);
      t[4] = f2bf(w1[0]); t[5] = f2bf(w1[1]); t[6] = f2bf(w1[2]); t[7] = f2bf(w1[3]);
      pa[kh] = t;
    }

    // O += P @ V
#pragma unroll
    for (int dt = 0; dt < 4; ++dt) {
      const short* vrow = Vh + (size_t)(dt * 16 + lr) * SEQ + k0 + lg * 8;
      bf16x8 vb0 = *(const bf16x8*)(vrow);
      bf16x8 vb1 = *(const bf16x8*)(vrow + 32);
      o[dt] = __builtin_amdgcn_mfma_f32_16x16x32_bf16(pa[0], vb0, o[dt], 0, 0, 0);
      o[dt] = __builtin_amdgcn_mfma_f32_16x16x32_bf16(pa[1], vb1, o[dt], 0, 0, 0);
    }
  }

  // ---- combine the 4 waves' partials -------------------------------------
  __syncthreads();  // all waves done with their plds regions
#pragma unroll
  for (int dt = 0; dt < 4; ++dt)
#pragma unroll
    for (int r = 0; r < 4; ++r)
      obp[((w * 4 + dt) * 4 + r) * 64 + lane] = o[dt][r];
#pragma unroll
  for (int r = 0; r < 4; ++r) {
    mbp[(w * 4 + r) * 64 + lane] = m[r];
    lbp[(w * 4 + r) * 64 + lane] = ll[r];
  }
  __syncthreads();

  // wave w produces output columns dt = w
#pragma unroll
  for (int r = 0; r < 4; ++r) {
    float m0 = mbp[(0 * 4 + r) * 64 + lane];
    float m1 = mbp[(1 * 4 + r) * 64 + lane];
    float m2 = mbp[(2 * 4 + r) * 64 + lane];
    float m3 = mbp[(3 * 4 + r) * 64 + lane];
    float mx = fmaxf(fmaxf(m0, m1), fmaxf(m2, m3));
    float f0 = exp2f(m0 - mx), f1 = exp2f(m1 - mx);
    float f2 = exp2f(m2 - mx), f3 = exp2f(m3 - mx);
    float lt = f0 * lbp[(0 * 4 + r) * 64 + lane] + f1 * lbp[(1 * 4 + r) * 64 + lane]
             + f2 * lbp[(2 * 4 + r) * 64 + lane] + f3 * lbp[(3 * 4 + r) * 64 + lane];
    float ot = f0 * obp[((0 * 4 + w) * 4 + r) * 64 + lane]
             + f1 * obp[((1 * 4 + w) * 4 + r) * 64 + lane]
             + f2 * obp[((2 * 4 + w) * 4 + r) * 64 + lane]
             + f3 * obp[((3 * 4 + w) * 4 + r) * 64 + lane];
    int row = q0 + 4 * lg + r;
    Out[hqb + (size_t)row * HD + w * 16 + lr] = ot / lt;
  }
}

// ---------------- fallback (self-contained, f32 inputs) ------------------------
__global__ __launch_bounds__(64) void attn_fwd_fallback(
    const float* __restrict__ Q, const float* __restrict__ K,
    const float* __restrict__ V, float* __restrict__ Out) {
  const int lane = threadIdx.x & 63;
  const int lr = lane & 15;
  const int lg = lane >> 4;
  const int q0 = blockIdx.x * 16;
  const size_t hb = (size_t)blockIdx.y * SEQ * HD;
  const float LOG2E = 1.4426950408889634f;

  bf16x8 qa[2];
  {
    const float* qrow = Q + hb + (size_t)(q0 + lr) * HD;
#pragma unroll
    for (int dh = 0; dh < 2; ++dh) {
      const float* p = qrow + dh * 32 + lg * 8;
      bf16x8 t;
#pragma unroll
      for (int i = 0; i < 8; ++i) t[i] = f2bf(p[i] * 0.125f);
      qa[dh] = t;
    }
  }
  f32x4 o[4];
#pragma unroll
  for (int dt = 0; dt < 4; ++dt) o[dt] = (f32x4){0.f, 0.f, 0.f, 0.f};
  float m[4], ll[4];
#pragma unroll
  for (int r = 0; r < 4; ++r) { m[r] = -INFINITY; ll[r] = 0.f; }
  __shared__ float plds[16][33];
  const int nsteps = (q0 + 16 + 31) >> 5;
  for (int s = 0; s < nsteps; ++s) {
    const int k0 = s * 32;
    bf16x8 kb[2][2];
#pragma unroll
    for (int ct = 0; ct < 2; ++ct) {
      const float* krow = K + hb + (size_t)(k0 + ct * 16 + lr) * HD;
#pragma unroll
      for (int dh = 0; dh < 2; ++dh) {
        const float* p = krow + dh * 32 + lg * 8;
        bf16x8 t;
#pragma unroll
        for (int i = 0; i < 8; ++i) t[i] = f2bf(p[i]);
        kb[ct][dh] = t;
      }
    }
    f32x4 sc[2];
#pragma unroll
    for (int ct = 0; ct < 2; ++ct) {
      f32x4 z = (f32x4){0.f, 0.f, 0.f, 0.f};
      z = __builtin_amdgcn_mfma_f32_16x16x32_bf16(qa[0], kb[ct][0], z, 0, 0, 0);
      z = __builtin_amdgcn_mfma_f32_16x16x32_bf16(qa[1], kb[ct][1], z, 0, 0, 0);
      sc[ct] = z;
    }
    if (s == nsteps - 1) {
#pragma unroll
      for (int ct = 0; ct < 2; ++ct)
#pragma unroll
        for (int r = 0; r < 4; ++r) {
          int col = k0 + ct * 16 + lr;
          int row = q0 + 4 * lg + r;
          if (col > row) sc[ct][r] = -INFINITY;
        }
    }
    float mx[4];
#pragma unroll
    for (int r = 0; r < 4; ++r) mx[r] = fmaxf(sc[0][r], sc[1][r]);
#pragma unroll
    for (int off = 1; off < 16; off <<= 1)
#pragma unroll
      for (int r = 0; r < 4; ++r) mx[r] = fmaxf(mx[r], __shfl_xor(mx[r], off, 64));
    float fac[4], pr[2][4], rs[4];
#pragma unroll
    for (int r = 0; r < 4; ++r) {
      float mn = fmaxf(m[r], mx[r]);
      fac[r] = exp2f((m[r] - mn) * LOG2E);
      m[r] = mn;
      float sum = 0.f;
#pragma unroll
      for (int ct = 0; ct < 2; ++ct) {
        float p = exp2f((sc[ct][r] - mn) * LOG2E);
        pr[ct][r] = p;
        sum += p;
      }
      rs[r] = sum;
    }
#pragma unroll
    for (int off = 1; off < 16; off <<= 1)
#pragma unroll
      for (int r = 0; r < 4; ++r) rs[r] += __shfl_xor(rs[r], off, 64);
#pragma unroll
    for (int r = 0; r < 4; ++r) ll[r] = ll[r] * fac[r] + rs[r];
#pragma unroll
    for (int dt = 0; dt < 4; ++dt)
#pragma unroll
      for (int r = 0; r < 4; ++r) o[dt][r] *= fac[r];
    __syncthreads();
#pragma unroll
    for (int ct = 0; ct < 2; ++ct)
#pragma unroll
      for (int r = 0; r < 4; ++r)
        plds[4 * lg + r][ct * 16 + lr] = pr[ct][r];
    __syncthreads();
    bf16x8 pa;
    {
      const float* p = &plds[lr][lg * 8];
#pragma unroll
      for (int i = 0; i < 8; ++i) pa[i] = f2bf(p[i]);
    }
#pragma unroll
    for (int dt = 0; dt < 4; ++dt) {
      const float* vcol = V + hb + (size_t)(k0 + lg * 8) * HD + dt * 16 + lr;
      bf16x8 vb;
#pragma unroll
      for (int i = 0; i < 8; ++i) vb[i] = f2bf(vcol[(size_t)i * HD]);
      o[dt] = __builtin_amdgcn_mfma_f32_16x16x32_bf16(pa, vb, o[dt], 0, 0, 0);
    }
  }
#pragma unroll
  for (int dt = 0; dt < 4; ++dt)
#pragma unroll
    for (int r = 0; r < 4; ++r) {
      int row = q0 + 4 * lg + r;
      Out[hb + (size_t)row * HD + dt * 16 + lr] = o[dt][r] / ll[r];
    }
}

extern "C" void kernel_launch(void* const* d_in, const int* in_sizes, int n_in,
                              void* d_out, int out_size, void* d_ws, size_t ws_size,
                              hipStream_t stream) {
  const float* q = (const float*)d_in[0];
  const float* k = (const float*)d_in[1];
  const float* v = (const float*)d_in[2];
  float* out = (float*)d_out;

  const size_t elems = (size_t)NH * SEQ * HD;      // 2,097,152
  const size_t need = 2 * elems * sizeof(short);   // 8 MB

  if (ws_size >= need) {
    short* Kb = (short*)d_ws;
    short* Vt = Kb + elems;
    conv_kv_kernel<<<dim3(SEQ / 64, NH), 256, 0, stream>>>(k, v, Kb, Vt);
    attn_fwd_kernel<<<dim3(SEQ / 16, NH), 256, 0, stream>>>(q, Kb, Vt, out);
  } else {
    attn_fwd_fallback<<<dim3(SEQ / 16, NH), dim3(64), 0, stream>>>(q, k, v, out);
  }
}

// Round 5
// 84.762 us; speedup vs baseline: 2.7189x; 1.2933x over previous
//
#include <hip/hip_runtime.h>
#include <hip/hip_bf16.h>
#include <math.h>

#define SEQ 2048
#define NH  16
#define HD  64

typedef __attribute__((ext_vector_type(8)))  short bf16x8;
typedef __attribute__((ext_vector_type(4)))  float f32x4;
typedef __attribute__((ext_vector_type(16))) float f32x16;

static __device__ inline short f2bf(float f) {
  union { float f; unsigned u; } x; x.f = f;
  unsigned u = x.u;
  unsigned r = (u + 0x7fffu + ((u >> 16) & 1u)) >> 16;  // RNE
  return (short)r;
}
// pack two f32 (even kv, odd kv) into one u32 of 2 bf16 (lo = even)
static __device__ inline unsigned pack2(float e, float o) {
  return ((unsigned)(unsigned short)f2bf(o) << 16) | (unsigned)(unsigned short)f2bf(e);
}

// ---- fused prepass: K f32->bf16 (same layout) + V f32->bf16 transposed [H][D][S]
__global__ __launch_bounds__(256) void conv_kv_kernel(
    const float* __restrict__ K, const float* __restrict__ V,
    short* __restrict__ Kb, short* __restrict__ Vt) {
  __shared__ short tile[64][72];
  const int h = blockIdx.y;
  const int s0 = blockIdx.x * 64;
  const int t = threadIdx.x;
  const int r = t >> 2;
  const int c0 = (t & 3) * 16;

  const size_t rowoff = ((size_t)h * SEQ + s0 + r) * HD + c0;

  {
    const float* ks = K + rowoff;
    bf16x8 k0, k1;
#pragma unroll
    for (int j = 0; j < 2; ++j) {
      float4 a = *(const float4*)(ks + j * 8);
      float4 b = *(const float4*)(ks + j * 8 + 4);
      bf16x8 o;
      o[0] = f2bf(a.x); o[1] = f2bf(a.y); o[2] = f2bf(a.z); o[3] = f2bf(a.w);
      o[4] = f2bf(b.x); o[5] = f2bf(b.y); o[6] = f2bf(b.z); o[7] = f2bf(b.w);
      if (j == 0) k0 = o; else k1 = o;
    }
    short* kd = Kb + rowoff;
    *(bf16x8*)(kd) = k0;
    *(bf16x8*)(kd + 8) = k1;
  }
  {
    const float* vs = V + rowoff;
#pragma unroll
    for (int j = 0; j < 4; ++j) {
      float4 a = *(const float4*)(vs + j * 4);
      tile[r][c0 + j * 4 + 0] = f2bf(a.x);
      tile[r][c0 + j * 4 + 1] = f2bf(a.y);
      tile[r][c0 + j * 4 + 2] = f2bf(a.z);
      tile[r][c0 + j * 4 + 3] = f2bf(a.w);
    }
    __syncthreads();
    short* dst = Vt + ((size_t)h * HD + r) * SEQ + s0 + c0;
    bf16x8 o0, o1;
#pragma unroll
    for (int j = 0; j < 8; ++j) o0[j] = tile[c0 + j][r];
#pragma unroll
    for (int j = 0; j < 8; ++j) o1[j] = tile[c0 + 8 + j][r];
    *(bf16x8*)(dst) = o0;
    *(bf16x8*)(dst + 8) = o1;
  }
}

// ---- main: swapped-operand 32x32 flash attention --------------------------------
// 2 waves/block, each wave owns all 32 q-rows, waves split KV tiles (stride 2).
// mfma_f32_32x32x16_bf16 layouts:
//   A: row=lane&31, k=(lane>>5)*8+i      B: col=lane&31, k=(lane>>5)*8+i
//   C/D: col=lane&31, row=(reg&3)+8*(reg>>2)+4*(lane>>5)
// QK^T swapped: st = mfma(K, Q) -> S^T[kv][q]: q=lane&31 (lane-local rows!)
// PV  swapped: ot = mfma(V^T, P^T) -> O^T[d][q]: q=lane&31 (in-lane rescale)
__global__ __launch_bounds__(128, 2) void attn_fwd_kernel(
    const float* __restrict__ Q, const short* __restrict__ Kb,
    const short* __restrict__ Vt, float* __restrict__ Out) {
  const int tid = threadIdx.x;
  const int w = tid >> 6;        // wave 0/1
  const int lane = tid & 63;
  const int ql = lane & 31;      // q-row owned by this lane
  const int hi = lane >> 5;
  const int qt = gridDim.x - 1 - blockIdx.x;   // heavy tiles first
  const int q0 = qt * 32;
  const int h = blockIdx.y;
  const size_t hqb = (size_t)h * SEQ * HD;
  const short* Kh = Kb + (size_t)h * SEQ * HD;
  const short* Vh = Vt + (size_t)h * HD * SEQ;

  __shared__ float lds_o1[64 * 32];   // wave1 O^T partials
  __shared__ float lds_ml[128];       // [0:64) m1, [64:128) l1
  __shared__ float lds_tr[32 * 68];   // output transpose buffer

  // Q B-fragments, pre-scaled by 0.125*log2(e) (log2-domain softmax)
  const float QSCALE = 0.125f * 1.4426950408889634f;
  bf16x8 qa[4];
  {
    const float* qbase = Q + hqb + (size_t)(q0 + ql) * HD + 8 * hi;
#pragma unroll
    for (int c = 0; c < 4; ++c) {
      const float* p = qbase + 16 * c;
      float4 a = *(const float4*)p;
      float4 b = *(const float4*)(p + 4);
      bf16x8 t;
      t[0] = f2bf(a.x * QSCALE); t[1] = f2bf(a.y * QSCALE);
      t[2] = f2bf(a.z * QSCALE); t[3] = f2bf(a.w * QSCALE);
      t[4] = f2bf(b.x * QSCALE); t[5] = f2bf(b.y * QSCALE);
      t[6] = f2bf(b.z * QSCALE); t[7] = f2bf(b.w * QSCALE);
      qa[c] = t;
    }
  }

  f32x16 ot0, ot1;   // O^T acc: d-tiles 0 (d 0..31) and 1 (d 32..63)
#pragma unroll
  for (int r = 0; r < 16; ++r) { ot0[r] = 0.f; ot1[r] = 0.f; }
  float m = -INFINITY, ll = 0.f;

  const int nsteps = (q0 + 32 + 63) >> 6;   // causal KV tiles of 64
  for (int s = w; s < nsteps; s += 2) {
    const int k0 = s * 64;
    const bool diag = (s == nsteps - 1);
    const bool t1live = (k0 + 32) <= (q0 + 31);  // kv-subtile 1 has any valid col

    // loads: K A-frags (rows=kv), V^T A-frags (rows=d, k=kv)
    bf16x8 kb0[4], kb1[4], va0[4], va1[4];
    {
      const short* kr = Kh + (size_t)(k0 + ql) * HD + 8 * hi;
#pragma unroll
      for (int c = 0; c < 4; ++c) kb0[c] = *(const bf16x8*)(kr + 16 * c);
#pragma unroll
      for (int c = 0; c < 4; ++c) kb1[c] = *(const bf16x8*)(kr + 32 * HD + 16 * c);
      const short* vr0 = Vh + (size_t)ql * SEQ + k0 + 8 * hi;
#pragma unroll
      for (int cc = 0; cc < 4; ++cc) {
        va0[cc] = *(const bf16x8*)(vr0 + 16 * cc);
        va1[cc] = *(const bf16x8*)(vr0 + 32 * SEQ + 16 * cc);
      }
    }

    // S^T tiles (kv 32-halves), chain over D=64 in 4 K=16 slices
    f32x16 st0, st1;
#pragma unroll
    for (int r = 0; r < 16; ++r) { st0[r] = 0.f; st1[r] = -INFINITY; }
#pragma unroll
    for (int c = 0; c < 4; ++c)
      st0 = __builtin_amdgcn_mfma_f32_32x32x16_bf16(kb0[c], qa[c], st0, 0, 0, 0);
    if (t1live) {
#pragma unroll
      for (int r = 0; r < 16; ++r) st1[r] = 0.f;
#pragma unroll
      for (int c = 0; c < 4; ++c)
        st1 = __builtin_amdgcn_mfma_f32_32x32x16_bf16(kb1[c], qa[c], st1, 0, 0, 0);
    }

    // causal mask (diagonal step only)
    const int qg = q0 + ql;
    if (diag) {
#pragma unroll
      for (int r = 0; r < 16; ++r) {
        int kv = k0 + (r & 3) + 8 * (r >> 2) + 4 * hi;
        if (kv > qg) st0[r] = -INFINITY;
        if (kv + 32 > qg) st1[r] = -INFINITY;
      }
    }

    // online softmax: row is lane-local; one cross-lane hop (lane^32)
    float mx = st0[0];
#pragma unroll
    for (int r = 1; r < 16; ++r) mx = fmaxf(mx, st0[r]);
#pragma unroll
    for (int r = 0; r < 16; ++r) mx = fmaxf(mx, st1[r]);
    mx = fmaxf(mx, __shfl_xor(mx, 32, 64));
    float mn = fmaxf(m, mx);
    float fac = exp2f(m - mn);
    m = mn;
    float rs = 0.f;
#pragma unroll
    for (int r = 0; r < 16; ++r) { float p = exp2f(st0[r] - mn); st0[r] = p; rs += p; }
#pragma unroll
    for (int r = 0; r < 16; ++r) { float p = exp2f(st1[r] - mn); st1[r] = p; rs += p; }
    rs += __shfl_xor(rs, 32, 64);
    ll = ll * fac + rs;
#pragma unroll
    for (int r = 0; r < 16; ++r) { ot0[r] *= fac; ot1[r] *= fac; }

    // pack P to bf16 pairs: u32 mm holds kv pair base 8*(mm>>1)+4*hi+2*(mm&1)
    unsigned pk0[8], pk1[8], rv0[8], rv1[8];
#pragma unroll
    for (int mm = 0; mm < 8; ++mm) {
      int re = 4 * (mm >> 1) + 2 * (mm & 1);
      pk0[mm] = pack2(st0[re], st0[re + 1]);
      pk1[mm] = pack2(st1[re], st1[re + 1]);
    }
#pragma unroll
    for (int mm = 0; mm < 8; ++mm) {
      rv0[mm] = (unsigned)__shfl_xor((int)pk0[mm], 32, 64);
      rv1[mm] = (unsigned)__shfl_xor((int)pk1[mm], 32, 64);
    }

    // PV: B-frag for chain cc needs kv = 16*cc + 8*hi + 0..7 (as 4 u32 pairs)
    //   hi=0: {pk[4ch],pk[4ch+1],rv[4ch],rv[4ch+1]}
    //   hi=1: {rv[4ch+2],rv[4ch+3],pk[4ch+2],pk[4ch+3]}
#pragma unroll
    for (int ch = 0; ch < 2; ++ch) {   // tile 0, cc = ch
      union { unsigned u[4]; bf16x8 v; } pb;
      pb.u[0] = hi ? rv0[4 * ch + 2] : pk0[4 * ch];
      pb.u[1] = hi ? rv0[4 * ch + 3] : pk0[4 * ch + 1];
      pb.u[2] = hi ? pk0[4 * ch + 2] : rv0[4 * ch];
      pb.u[3] = hi ? pk0[4 * ch + 3] : rv0[4 * ch + 1];
      ot0 = __builtin_amdgcn_mfma_f32_32x32x16_bf16(va0[ch], pb.v, ot0, 0, 0, 0);
      ot1 = __builtin_amdgcn_mfma_f32_32x32x16_bf16(va1[ch], pb.v, ot1, 0, 0, 0);
    }
    if (t1live) {
#pragma unroll
      for (int ch = 0; ch < 2; ++ch) {  // tile 1, cc = 2+ch
        union { unsigned u[4]; bf16x8 v; } pb;
        pb.u[0] = hi ? rv1[4 * ch + 2] : pk1[4 * ch];
        pb.u[1] = hi ? rv1[4 * ch + 3] : pk1[4 * ch + 1];
        pb.u[2] = hi ? pk1[4 * ch + 2] : rv1[4 * ch];
        pb.u[3] = hi ? pk1[4 * ch + 3] : rv1[4 * ch + 1];
        ot0 = __builtin_amdgcn_mfma_f32_32x32x16_bf16(va0[2 + ch], pb.v, ot0, 0, 0, 0);
        ot1 = __builtin_amdgcn_mfma_f32_32x32x16_bf16(va1[2 + ch], pb.v, ot1, 0, 0, 0);
      }
    }
  }

  // ---- combine the 2 waves' partials, transpose, store ----------------------
  if (w == 1) {
#pragma unroll
    for (int r = 0; r < 16; ++r) {
      lds_o1[lane * 32 + r] = ot0[r];
      lds_o1[lane * 32 + 16 + r] = ot1[r];
    }
    lds_ml[lane] = m;
    lds_ml[64 + lane] = ll;
  }
  __syncthreads();
  if (w == 0) {
    float m1 = lds_ml[lane], l1 = lds_ml[64 + lane];
    float mxx = fmaxf(m, m1);
    float f0 = exp2f(m - mxx), f1 = exp2f(m1 - mxx);
    float lt = f0 * ll + f1 * l1;
    float inv = 1.f / lt;
#pragma unroll
    for (int r = 0; r < 16; ++r) {
      float o0m = (f0 * ot0[r] + f1 * lds_o1[lane * 32 + r]) * inv;
      float o1m = (f0 * ot1[r] + f1 * lds_o1[lane * 32 + 16 + r]) * inv;
      int d = (r & 3) + 8 * (r >> 2) + 4 * hi;
      lds_tr[ql * 68 + d] = o0m;
      lds_tr[ql * 68 + 32 + d] = o1m;
    }
    // same-wave DS ordering: safe to read other lanes' writes after in-order DS ops
    int row = lane >> 1;
    int half = (lane & 1) * 32;
    const float* tr = &lds_tr[row * 68 + half];
    float* outp = Out + hqb + (size_t)(q0 + row) * HD + half;
#pragma unroll
    for (int j = 0; j < 8; ++j)
      *(f32x4*)(outp + 4 * j) = *(const f32x4*)(tr + 4 * j);
  }
}

// ---------------- fallback (self-contained, f32 inputs) ------------------------
typedef __attribute__((ext_vector_type(4))) float f32x4_t;
__global__ __launch_bounds__(64) void attn_fwd_fallback(
    const float* __restrict__ Q, const float* __restrict__ K,
    const float* __restrict__ V, float* __restrict__ Out) {
  const int lane = threadIdx.x & 63;
  const int lr = lane & 15;
  const int lg = lane >> 4;
  const int q0 = blockIdx.x * 16;
  const size_t hb = (size_t)blockIdx.y * SEQ * HD;
  const float LOG2E = 1.4426950408889634f;

  bf16x8 qa[2];
  {
    const float* qrow = Q + hb + (size_t)(q0 + lr) * HD;
#pragma unroll
    for (int dh = 0; dh < 2; ++dh) {
      const float* p = qrow + dh * 32 + lg * 8;
      bf16x8 t;
#pragma unroll
      for (int i = 0; i < 8; ++i) t[i] = f2bf(p[i] * 0.125f);
      qa[dh] = t;
    }
  }
  f32x4 o[4];
#pragma unroll
  for (int dt = 0; dt < 4; ++dt) o[dt] = (f32x4){0.f, 0.f, 0.f, 0.f};
  float m[4], ll[4];
#pragma unroll
  for (int r = 0; r < 4; ++r) { m[r] = -INFINITY; ll[r] = 0.f; }
  __shared__ float plds[16][33];
  const int nsteps = (q0 + 16 + 31) >> 5;
  for (int s = 0; s < nsteps; ++s) {
    const int k0 = s * 32;
    bf16x8 kb[2][2];
#pragma unroll
    for (int ct = 0; ct < 2; ++ct) {
      const float* krow = K + hb + (size_t)(k0 + ct * 16 + lr) * HD;
#pragma unroll
      for (int dh = 0; dh < 2; ++dh) {
        const float* p = krow + dh * 32 + lg * 8;
        bf16x8 t;
#pragma unroll
        for (int i = 0; i < 8; ++i) t[i] = f2bf(p[i]);
        kb[ct][dh] = t;
      }
    }
    f32x4 sc[2];
#pragma unroll
    for (int ct = 0; ct < 2; ++ct) {
      f32x4 z = (f32x4){0.f, 0.f, 0.f, 0.f};
      z = __builtin_amdgcn_mfma_f32_16x16x32_bf16(qa[0], kb[ct][0], z, 0, 0, 0);
      z = __builtin_amdgcn_mfma_f32_16x16x32_bf16(qa[1], kb[ct][1], z, 0, 0, 0);
      sc[ct] = z;
    }
    if (s == nsteps - 1) {
#pragma unroll
      for (int ct = 0; ct < 2; ++ct)
#pragma unroll
        for (int r = 0; r < 4; ++r) {
          int col = k0 + ct * 16 + lr;
          int row = q0 + 4 * lg + r;
          if (col > row) sc[ct][r] = -INFINITY;
        }
    }
    float mx[4];
#pragma unroll
    for (int r = 0; r < 4; ++r) mx[r] = fmaxf(sc[0][r], sc[1][r]);
#pragma unroll
    for (int off = 1; off < 16; off <<= 1)
#pragma unroll
      for (int r = 0; r < 4; ++r) mx[r] = fmaxf(mx[r], __shfl_xor(mx[r], off, 64));
    float fac[4], pr[2][4], rs[4];
#pragma unroll
    for (int r = 0; r < 4; ++r) {
      float mn = fmaxf(m[r], mx[r]);
      fac[r] = exp2f((m[r] - mn) * LOG2E);
      m[r] = mn;
      float sum = 0.f;
#pragma unroll
      for (int ct = 0; ct < 2; ++ct) {
        float p = exp2f((sc[ct][r] - mn) * LOG2E);
        pr[ct][r] = p;
        sum += p;
      }
      rs[r] = sum;
    }
#pragma unroll
    for (int off = 1; off < 16; off <<= 1)
#pragma unroll
      for (int r = 0; r < 4; ++r) rs[r] += __shfl_xor(rs[r], off, 64);
#pragma unroll
    for (int r = 0; r < 4; ++r) ll[r] = ll[r] * fac[r] + rs[r];
#pragma unroll
    for (int dt = 0; dt < 4; ++dt)
#pragma unroll
      for (int r = 0; r < 4; ++r) o[dt][r] *= fac[r];
    __syncthreads();
#pragma unroll
    for (int ct = 0; ct < 2; ++ct)
#pragma unroll
      for (int r = 0; r < 4; ++r)
        plds[4 * lg + r][ct * 16 + lr] = pr[ct][r];
    __syncthreads();
    bf16x8 pa;
    {
      const float* p = &plds[lr][lg * 8];
#pragma unroll
      for (int i = 0; i < 8; ++i) pa[i] = f2bf(p[i]);
    }
#pragma unroll
    for (int dt = 0; dt < 4; ++dt) {
      const float* vcol = V + hb + (size_t)(k0 + lg * 8) * HD + dt * 16 + lr;
      bf16x8 vb;
#pragma unroll
      for (int i = 0; i < 8; ++i) vb[i] = f2bf(vcol[(size_t)i * HD]);
      o[dt] = __builtin_amdgcn_mfma_f32_16x16x32_bf16(pa, vb, o[dt], 0, 0, 0);
    }
  }
#pragma unroll
  for (int dt = 0; dt < 4; ++dt)
#pragma unroll
    for (int r = 0; r < 4; ++r) {
      int row = q0 + 4 * lg + r;
      Out[hb + (size_t)row * HD + dt * 16 + lr] = o[dt][r] / ll[r];
    }
}

extern "C" void kernel_launch(void* const* d_in, const int* in_sizes, int n_in,
                              void* d_out, int out_size, void* d_ws, size_t ws_size,
                              hipStream_t stream) {
  const float* q = (const float*)d_in[0];
  const float* k = (const float*)d_in[1];
  const float* v = (const float*)d_in[2];
  float* out = (float*)d_out;

  const size_t elems = (size_t)NH * SEQ * HD;      // 2,097,152
  const size_t need = 2 * elems * sizeof(short);   // 8 MB

  if (ws_size >= need) {
    short* Kb = (short*)d_ws;
    short* Vt = Kb + elems;
    conv_kv_kernel<<<dim3(SEQ / 64, NH), 256, 0, stream>>>(k, v, Kb, Vt);
    attn_fwd_kernel<<<dim3(SEQ / 32, NH), 128, 0, stream>>>(q, Kb, Vt, out);
  } else {
    attn_fwd_fallback<<<dim3(SEQ / 16, NH), dim3(64), 0, stream>>>(q, k, v, out);
  }
}